// Round 5
// baseline (230.087 us; speedup 1.0000x reference)
//
#include <hip/hip_runtime.h>
#include <hip/hip_bf16.h>
#include <stdint.h>
#include <stddef.h>

// MMD via single signed 2N x 2N RBF gram, lower triangle only.
// Round 12b: occupancy doubling (resubmit #2; two container-level failures,
// de-risked by removing __builtin_elementwise_fma — the only novel construct
// vs known-good kernels; replaced with scalar fmaf).
// LDS = 2 x 16 KB K=128 slices (32 KB, was 64 KB); af kc-resident (32 VGPRs,
// reloaded per slice from L2-hot Zf8); a_i reloaded per tile; target unified
// regs <= 128 -> launch_bounds(256,4) = 4 blocks/CU = 16 waves/CU (was 8).
// Epilogue: fmaf + exp2, column factor folded multiplicatively (eb=exp2(b_j)).

#define N_PTS   8192
#define DIM     256
#define TWO_N   16384
#define CSTRIDE 16

#define AS1 __attribute__((address_space(1)))
#define AS3 __attribute__((address_space(3)))

typedef __attribute__((ext_vector_type(4))) float f32x4;
typedef __attribute__((ext_vector_type(4))) int   i32x4;
typedef __attribute__((ext_vector_type(8))) int   i32x8;

// ---------------------------------------------------------------------------
// Prep: fp32 -> fp8 e4m3 (row-major) + c2-scaled fp32 row norms + zero output.
// n2[row] = c2 * |z_row|^2, c2 = -log2e/sigma (epilogue adds directly).
// ---------------------------------------------------------------------------
__global__ __launch_bounds__(256) void mmd_prep(const float* __restrict__ X,
                                                const float* __restrict__ Y,
                                                const int* __restrict__ sigmap,
                                                unsigned char* __restrict__ Zf8,
                                                float* __restrict__ n2,
                                                float* __restrict__ out) {
    if (blockIdx.x == 0 && threadIdx.x == 0) out[0] = 0.0f;

    const int wave = threadIdx.x >> 6;
    const int lane = threadIdx.x & 63;
    const int row  = blockIdx.x * 4 + wave;          // 0 .. TWO_N-1

    const float* src = (row < N_PTS) ? (X + (size_t)row * DIM)
                                     : (Y + (size_t)(row - N_PTS) * DIM);
    float4 v = ((const float4*)src)[lane];           // 64 lanes x 4 = 256

    float s = v.x * v.x + v.y * v.y + v.z * v.z + v.w * v.w;
#pragma unroll
    for (int off = 32; off; off >>= 1) s += __shfl_down(s, off, 64);
    if (lane == 0) {
        const float c2 = -1.4426950408889634f / (float)(*sigmap);
        n2[row] = c2 * s;
    }

    const int p01 = __builtin_amdgcn_cvt_pk_fp8_f32(v.x, v.y, 0, false);
    const int p23 = __builtin_amdgcn_cvt_pk_fp8_f32(v.z, v.w, 0, false);
    const unsigned int pk = ((unsigned)p01 & 0xffffu) | ((unsigned)p23 << 16);
    *(unsigned int*)(Zf8 + (size_t)row * DIM + (size_t)lane * 4) = pk;
}

// ---------------------------------------------------------------------------
// Main. grid = 128*16; br = 127 - (bid>>4) (heavy first), cc = bid & 15;
// empty blocks (cc > br) exit. 4 waves in 2x2; wave (wm,wn) owns 64x64.
// Per tile bc: 2 K=128 slices, each: [af loads][barrier][stage next slice]
// [8 ds_read_b128 -> 16 MFMA 16x16x128 MX-fp8]. Epilogue after kc=1.
// LDS slice layout: per col 128 B = 8 x 16B chunks, chunk slot = j ^ (col&7).
// ---------------------------------------------------------------------------
__global__ __launch_bounds__(256, 4) void mmd_main(const unsigned char* __restrict__ Zf8,
                                                   const float* __restrict__ n2,
                                                   const int* __restrict__ sigmap,
                                                   float* __restrict__ out) {
    __shared__ char smem_b[32768];   // 2 x 16 KB slice buffers
    __shared__ float wsum[4];

    const int bid = (int)blockIdx.x;
    const int br  = 127 - (bid >> 4);
    const int cc  = bid & 15;
    if (cc > br) return;

    const int t    = threadIdx.x;
    const int wave = t >> 6;
    const int lane = t & 63;
    const int wm   = wave >> 1;
    const int wn   = wave & 1;
    const int g    = lane >> 4;      // k-quad
    const int ml   = lane & 15;
    const int rowBase = br * 128;

    const float m2 = 2.8853900817779268f / (float)(*sigmap);   // 2*log2e/sigma
    const int   SC = 0x7f7f7f7f;     // E8M0 unit scales (2^0)

    // ---- staging invariants: 1024 16B chunks / 256 threads = 4 per thread
    // col = i*32 + (t>>3); swizzled source chunk gc = (t&7) ^ ((t>>3)&7)
    const int gbase = (t >> 3) * 256 + (((t & 7) ^ ((t >> 3) & 7)) * 16);
    const int lbase = t * 16;

    // ---- bf ds_read bases (two 16B halves of the lane's 32B) ----
    const int rb0 = (wn * 64 + ml) * 128 + ((((g * 2))     ^ (ml & 7)) * 16);
    const int rb1 = (wn * 64 + ml) * 128 + ((((g * 2) + 1) ^ (ml & 7)) * 16);

    // ---- af / a_i source bases ----
    const unsigned char* apB = Zf8 + (size_t)(rowBase + wm * 64 + ml) * 256 + g * 32;
    const float*         aiB = n2 + rowBase + wm * 64 + g * 4;

    const f32x4 zacc = {0.0f, 0.0f, 0.0f, 0.0f};

    // ---- prologue: stage slice (tt=0, kc=0) into buffer 0 ----
    {
        const unsigned char* sb = Zf8 + (size_t)cc * 128 * 256 + gbase;
#pragma unroll
        for (int i = 0; i < 4; ++i)
            __builtin_amdgcn_global_load_lds((const AS1 void*)(sb + i * 8192),
                                             (AS3 void*)(smem_b + i * 4096 + lbase), 16, 0, 0);
    }

    float block_acc = 0.0f;
    const int brX = (br < 64);
    const int nT  = (br - cc) / CSTRIDE + 1;
    int cur = 0;

    for (int tt = 0; tt < nT; ++tt) {
        const int bc = cc + tt * CSTRIDE;

        // per-tile multiplicative column factors (hidden under compute)
        float eb[4];
#pragma unroll
        for (int nt = 0; nt < 4; ++nt)
            eb[nt] = __builtin_amdgcn_exp2f(n2[bc * 128 + wn * 64 + nt * 16 + ml]);

        f32x4 acc[4][4];

#pragma unroll
        for (int kc = 0; kc < 2; ++kc) {
            // af for this kc: global (L2-hot), issued pre-barrier
            i32x8 af[4];
#pragma unroll
            for (int mt = 0; mt < 4; ++mt) {
                union { i32x4 h[2]; i32x8 v; } u;
                u.h[0] = *(const i32x4*)(apB + mt * 4096 + kc * 128);
                u.h[1] = *(const i32x4*)(apB + mt * 4096 + kc * 128 + 16);
                af[mt] = u.v;
            }

            __syncthreads();         // slice staged in buf cur; buf cur^1 free

            // stage next slice into the other buffer (overlaps compute)
            const int sN = tt * 2 + kc + 1;
            if (sN < nT * 2) {
                const unsigned char* sb = Zf8
                    + (size_t)(cc + (sN >> 1) * CSTRIDE) * 128 * 256
                    + (sN & 1) * 128 + gbase;
                char* dst = smem_b + (cur ^ 1) * 16384;
#pragma unroll
                for (int i = 0; i < 4; ++i)
                    __builtin_amdgcn_global_load_lds((const AS1 void*)(sb + i * 8192),
                                                     (AS3 void*)(dst + i * 4096 + lbase), 16, 0, 0);
            }

            // compute this slice: 4 nt x 4 mt MFMA
            const char* buf = smem_b + cur * 16384;
#pragma unroll
            for (int nt = 0; nt < 4; ++nt) {
                union { i32x4 h[2]; i32x8 v; } u;
                u.h[0] = *(const i32x4*)(buf + rb0 + nt * 2048);
                u.h[1] = *(const i32x4*)(buf + rb1 + nt * 2048);
                const i32x8 bf = u.v;
#pragma unroll
                for (int mt = 0; mt < 4; ++mt)
                    acc[mt][nt] = __builtin_amdgcn_mfma_scale_f32_16x16x128_f8f6f4(
                        af[mt], bf, (kc == 0) ? zacc : acc[mt][nt],
                        0, 0, 0, SC, 0, SC);
            }
            cur ^= 1;
        }

        // ---- epilogue: fmaf + exp2, column factor multiplicative ----
        float ts0 = 0.0f, ts1 = 0.0f, ts2 = 0.0f, ts3 = 0.0f;
#pragma unroll
        for (int mt = 0; mt < 4; ++mt) {
            const float4 av = *(const float4*)(aiB + mt * 16);   // L1-hot, per tile
#pragma unroll
            for (int nt = 0; nt < 4; ++nt) {
                const float e = eb[nt];
                ts0 = fmaf(__builtin_amdgcn_exp2f(fmaf(acc[mt][nt][0], m2, av.x)), e, ts0);
                ts1 = fmaf(__builtin_amdgcn_exp2f(fmaf(acc[mt][nt][1], m2, av.y)), e, ts1);
                ts2 = fmaf(__builtin_amdgcn_exp2f(fmaf(acc[mt][nt][2], m2, av.z)), e, ts2);
                ts3 = fmaf(__builtin_amdgcn_exp2f(fmaf(acc[mt][nt][3], m2, av.w)), e, ts3);
            }
        }
        const float tsum = (ts0 + ts1) + (ts2 + ts3);
        const float sgn = ((bc < 64) == brX) ? 1.0f : -1.0f;
        const float w   = (bc == br) ? sgn : 2.0f * sgn;   // symmetry weight
        block_acc = fmaf(w, tsum, block_acc);
    }

    // ---- block reduction + single atomic ----
    float s = block_acc;
#pragma unroll
    for (int off = 32; off; off >>= 1) s += __shfl_down(s, off, 64);
    if (lane == 0) wsum[wave] = s;
    __syncthreads();
    if (t == 0)
        atomicAdd(out, (wsum[0] + wsum[1] + wsum[2] + wsum[3]) * (1.0f / 67108864.0f));
}

// ---------------------------------------------------------------------------
extern "C" void kernel_launch(void* const* d_in, const int* in_sizes, int n_in,
                              void* d_out, int out_size, void* d_ws, size_t ws_size,
                              hipStream_t stream) {
    const float* X      = (const float*)d_in[0];
    const float* Y      = (const float*)d_in[1];
    const int*   sigmap = (const int*)d_in[2];
    float*       out    = (float*)d_out;

    unsigned char* Zf8 = (unsigned char*)d_ws;                        // 4 MB
    float*         n2  = (float*)((char*)d_ws + (size_t)TWO_N * DIM);

    mmd_prep<<<TWO_N / 4, 256, 0, stream>>>(X, Y, sigmap, Zf8, n2, out);
    mmd_main<<<128 * CSTRIDE, 256, 0, stream>>>(Zf8, n2, sigmap, out);
}

// Round 6
// 113.761 us; speedup vs baseline: 2.0226x; 2.0226x over previous
//
#include <hip/hip_runtime.h>
#include <hip/hip_bf16.h>
#include <stdint.h>
#include <stddef.h>

// MMD via single signed 2N x 2N RBF gram, lower triangle only.
// Round 13: occupancy via COLUMN slicing. Slice = 64 cols x full K=256
// (16 KB), double-buffered (32 KB LDS). 4 waves in 4x1: wave tile 32 rows
// x 64 cols per slice -> acc[2][4] = 32 AGPRs (was 64), af[2][2] = 32 VGPRs
// resident. Full-K reduction completes per slice -> epilogue per slice.
// Register rule (r10/r12b evidence): total(arch+AGPR) <= 512/(waves/SIMD);
// here ~112 < 128 -> launch_bounds(256,4) = 4 blk/CU = 16 waves/CU (2x r11).
// Per-col LDS layout identical to r11's proven conflict-free 256B-row
// 16-slot XOR swizzle (slot s of col c holds global chunk s ^ (c&15)).

#define N_PTS   8192
#define DIM     256
#define TWO_N   16384
#define CSTRIDE 16

#define AS1 __attribute__((address_space(1)))
#define AS3 __attribute__((address_space(3)))

typedef __attribute__((ext_vector_type(4))) float f32x4;
typedef __attribute__((ext_vector_type(4))) int   i32x4;
typedef __attribute__((ext_vector_type(8))) int   i32x8;

// ---------------------------------------------------------------------------
// Prep: fp32 -> fp8 e4m3 (row-major) + c2-scaled fp32 row norms + zero output.
// n2[row] = c2 * |z_row|^2, c2 = -log2e/sigma (epilogue adds directly).
// ---------------------------------------------------------------------------
__global__ __launch_bounds__(256) void mmd_prep(const float* __restrict__ X,
                                                const float* __restrict__ Y,
                                                const int* __restrict__ sigmap,
                                                unsigned char* __restrict__ Zf8,
                                                float* __restrict__ n2,
                                                float* __restrict__ out) {
    if (blockIdx.x == 0 && threadIdx.x == 0) out[0] = 0.0f;

    const int wave = threadIdx.x >> 6;
    const int lane = threadIdx.x & 63;
    const int row  = blockIdx.x * 4 + wave;          // 0 .. TWO_N-1

    const float* src = (row < N_PTS) ? (X + (size_t)row * DIM)
                                     : (Y + (size_t)(row - N_PTS) * DIM);
    float4 v = ((const float4*)src)[lane];           // 64 lanes x 4 = 256

    float s = v.x * v.x + v.y * v.y + v.z * v.z + v.w * v.w;
#pragma unroll
    for (int off = 32; off; off >>= 1) s += __shfl_down(s, off, 64);
    if (lane == 0) {
        const float c2 = -1.4426950408889634f / (float)(*sigmap);
        n2[row] = c2 * s;
    }

    const int p01 = __builtin_amdgcn_cvt_pk_fp8_f32(v.x, v.y, 0, false);
    const int p23 = __builtin_amdgcn_cvt_pk_fp8_f32(v.z, v.w, 0, false);
    const unsigned int pk = ((unsigned)p01 & 0xffffu) | ((unsigned)p23 << 16);
    *(unsigned int*)(Zf8 + (size_t)row * DIM + (size_t)lane * 4) = pk;
}

// ---------------------------------------------------------------------------
// Main. grid = 128*16; br = 127 - (bid>>4) (heavy first), cc = bid & 15;
// empty blocks (cc > br) exit. 4 waves in 4x1; wave owns rows wave*32..+32.
// Per tile bc: 2 column-slices (h = 0,1; cols h*64..+64, full K=256).
// Per slice: [barrier][stage next slice][16 MFMA 16x16x128][epilogue-slice].
// LDS col row = 256 B = 16 x 16B slots; slot s holds global chunk s^(c&15).
// ---------------------------------------------------------------------------
__global__ __launch_bounds__(256, 4) void mmd_main(const unsigned char* __restrict__ Zf8,
                                                   const float* __restrict__ n2,
                                                   const int* __restrict__ sigmap,
                                                   float* __restrict__ out) {
    __shared__ char smem_b[32768];   // 2 x 16 KB col-slice buffers
    __shared__ float wsum[4];

    const int bid = (int)blockIdx.x;
    const int br  = 127 - (bid >> 4);
    const int cc  = bid & 15;
    if (cc > br) return;

    const int t    = threadIdx.x;
    const int wave = t >> 6;         // 0..3: 32-row group
    const int lane = t & 63;
    const int g    = lane >> 4;      // k-quad
    const int ml   = lane & 15;
    const int rowBase = br * 128;

    const float m2 = 2.8853900817779268f / (float)(*sigmap);   // 2*log2e/sigma
    const int   SC = 0x7f7f7f7f;     // E8M0 unit scales (2^0)

    // ---- staging invariants: 1024 16B chunks / 256 threads = 4 per thread
    // local col c = i*16 + (t>>4); slot s = t&15; source chunk = s ^ (c&15)
    const int gbase = (t >> 4) * 256 + (((t & 15) ^ (t >> 4)) * 16);
    const int lbase = t * 16;

    // ---- bf ds_read bases within a slice buffer (col = nt*16 + ml) ----
    // byte = col*256 + ((j ^ ml) * 16), j = kc*8 + g*2 (+1 for 2nd half)
    int rb0[2], rb1[2];
#pragma unroll
    for (int kc = 0; kc < 2; ++kc) {
        rb0[kc] = ml * 256 + (((kc * 8 + g * 2)     ^ ml) * 16);
        rb1[kc] = ml * 256 + (((kc * 8 + g * 2 + 1) ^ ml) * 16);
    }

    // ---- A fragments (full K, this wave's 32 rows): 32 VGPRs, resident ----
    i32x8 af[2][2];
#pragma unroll
    for (int mt = 0; mt < 2; ++mt) {
        const unsigned char* rp =
            Zf8 + (size_t)(rowBase + wave * 32 + mt * 16 + ml) * 256 + g * 32;
#pragma unroll
        for (int kc = 0; kc < 2; ++kc) {
            union { i32x4 h[2]; i32x8 v; } u;
            u.h[0] = *(const i32x4*)(rp + kc * 128);
            u.h[1] = *(const i32x4*)(rp + kc * 128 + 16);
            af[mt][kc] = u.v;
        }
    }
    // row-norm coefficients for this lane's 8 C rows (resident)
    float a_i[2][4];
#pragma unroll
    for (int mt = 0; mt < 2; ++mt)
#pragma unroll
        for (int rr = 0; rr < 4; ++rr)
            a_i[mt][rr] = n2[rowBase + wave * 32 + mt * 16 + g * 4 + rr];

    const f32x4 zacc = {0.0f, 0.0f, 0.0f, 0.0f};

    // ---- prologue: stage slice 0 (tile cc, cols 0..63) into buffer 0 ----
    {
        const unsigned char* sb = Zf8 + (size_t)cc * 128 * 256 + gbase;
#pragma unroll
        for (int i = 0; i < 4; ++i)
            __builtin_amdgcn_global_load_lds((const AS1 void*)(sb + i * 4096),
                                             (AS3 void*)(smem_b + i * 4096 + lbase), 16, 0, 0);
    }

    float block_acc = 0.0f;
    const int brX = (br < 64);
    const int nT  = (br - cc) / CSTRIDE + 1;
    const int nS  = nT * 2;
    int cur = 0;

    for (int ss = 0; ss < nS; ++ss) {
        const int bc = cc + (ss >> 1) * CSTRIDE;
        const int h  = ss & 1;
        const int colBase = bc * 128 + h * 64;       // global col of slice

        // per-slice multiplicative column factors
        float eb[4];
#pragma unroll
        for (int nt = 0; nt < 4; ++nt)
            eb[nt] = __builtin_amdgcn_exp2f(n2[colBase + nt * 16 + ml]);

        __syncthreads();             // slice ss staged in buf cur; cur^1 free

        // ---- stage next slice into the other buffer (overlaps compute) ----
        if (ss + 1 < nS) {
            const int bcN = cc + ((ss + 1) >> 1) * CSTRIDE;
            const int hN  = (ss + 1) & 1;
            const unsigned char* sb =
                Zf8 + (size_t)(bcN * 128 + hN * 64) * 256 + gbase;
            char* dst = smem_b + (cur ^ 1) * 16384;
#pragma unroll
            for (int i = 0; i < 4; ++i)
                __builtin_amdgcn_global_load_lds((const AS1 void*)(sb + i * 4096),
                                                 (AS3 void*)(dst + i * 4096 + lbase), 16, 0, 0);
        }

        // ---- compute: 4 nt x (2 mt x 2 kc) MFMA, full-K per slice ----
        const char* buf = smem_b + cur * 16384;
        f32x4 acc[2][4];
#pragma unroll
        for (int nt = 0; nt < 4; ++nt) {
#pragma unroll
            for (int kc = 0; kc < 2; ++kc) {
                union { i32x4 h[2]; i32x8 v; } u;
                u.h[0] = *(const i32x4*)(buf + nt * 4096 + rb0[kc]);
                u.h[1] = *(const i32x4*)(buf + nt * 4096 + rb1[kc]);
                const i32x8 bf = u.v;
#pragma unroll
                for (int mt = 0; mt < 2; ++mt)
                    acc[mt][nt] = __builtin_amdgcn_mfma_scale_f32_16x16x128_f8f6f4(
                        af[mt][kc], bf, (kc == 0) ? zacc : acc[mt][nt],
                        0, 0, 0, SC, 0, SC);
            }
        }

        // ---- epilogue for this slice ----
        float ts0 = 0.0f, ts1 = 0.0f, ts2 = 0.0f, ts3 = 0.0f;
#pragma unroll
        for (int mt = 0; mt < 2; ++mt)
#pragma unroll
            for (int nt = 0; nt < 4; ++nt) {
                const float e = eb[nt];
                ts0 = fmaf(__builtin_amdgcn_exp2f(fmaf(acc[mt][nt][0], m2, a_i[mt][0])), e, ts0);
                ts1 = fmaf(__builtin_amdgcn_exp2f(fmaf(acc[mt][nt][1], m2, a_i[mt][1])), e, ts1);
                ts2 = fmaf(__builtin_amdgcn_exp2f(fmaf(acc[mt][nt][2], m2, a_i[mt][2])), e, ts2);
                ts3 = fmaf(__builtin_amdgcn_exp2f(fmaf(acc[mt][nt][3], m2, a_i[mt][3])), e, ts3);
            }
        const float tsum = (ts0 + ts1) + (ts2 + ts3);

        const float sgn = ((bc < 64) == brX) ? 1.0f : -1.0f;
        const float w   = (bc == br) ? sgn : 2.0f * sgn;   // symmetry weight
        block_acc = fmaf(w, tsum, block_acc);
        cur ^= 1;
    }

    // ---- block reduction + single atomic ----
    float s = block_acc;
#pragma unroll
    for (int off = 32; off; off >>= 1) s += __shfl_down(s, off, 64);
    if (lane == 0) wsum[wave] = s;
    __syncthreads();
    if (t == 0)
        atomicAdd(out, (wsum[0] + wsum[1] + wsum[2] + wsum[3]) * (1.0f / 67108864.0f));
}

// ---------------------------------------------------------------------------
extern "C" void kernel_launch(void* const* d_in, const int* in_sizes, int n_in,
                              void* d_out, int out_size, void* d_ws, size_t ws_size,
                              hipStream_t stream) {
    const float* X      = (const float*)d_in[0];
    const float* Y      = (const float*)d_in[1];
    const int*   sigmap = (const int*)d_in[2];
    float*       out    = (float*)d_out;

    unsigned char* Zf8 = (unsigned char*)d_ws;                        // 4 MB
    float*         n2  = (float*)((char*)d_ws + (size_t)TWO_N * DIM);

    mmd_prep<<<TWO_N / 4, 256, 0, stream>>>(X, Y, sigmap, Zf8, n2, out);
    mmd_main<<<128 * CSTRIDE, 256, 0, stream>>>(Zf8, n2, sigmap, out);
}